// Round 2
// baseline (415.388 us; speedup 1.0000x reference)
//
#include <hip/hip_runtime.h>
#include <hip/hip_bf16.h>
#include <stdint.h>

// NBEATS MoE block — round 6: fully-fused persistent expert chain.
// Round-5 post-mortem: per-dispatch tuning is capped — 5 dispatches x 9.7
// GFLOP with 576 blocks each, 150MB of z round-trips, MFMA floor for the
// whole chain ~22us. This round fuses all 5 layers into ONE kernel:
//   - 64-row tiles, 288 blocks (8 experts x 36), e = bid&7 -> XCD-affine so
//     each expert's 2.2MB weights stay in one XCD's L2.
//   - z [64][512] bf16 in LDS (64KB, XOR-swizzled, single-buffered; layer
//     output stashed in regs across a barrier, then overwrites z).
//   - weights stream global->VGPR reg-staged 1 K-step ahead (no B-LDS, no
//     staging barriers; immediate-offset folded loads).
//   - swapped-operand MFMA: D = W_frag x z_frag -> lane holds col=m, rows=n
//     (m89 C/D map) -> z writeback is packed ds_write_b64, and the final
//     scatter gets 4 consecutive cols per lane.
//   - final layer N=640 as 2 passes of NF=5 per wave (acc <= 80 VGPR).
// gate/assign/transpose kernels unchanged from round 4/5.

#define B_ROWS 8192
#define I_DIM  512
#define H_DIM  512
#define E_NUM  8
#define T_DIM  608
#define T_PAD  640
#define CAP    2304   // rows per expert segment (capacity)
#define TPW    36     // 64-row tiles per expert = CAP/64
#define NB     288    // total chain blocks = E_NUM*TPW
#define NPAD   18432  // CAP*E_NUM

typedef unsigned short ushort_t;
typedef __attribute__((ext_vector_type(8))) __bf16 bf16x8;
typedef __attribute__((ext_vector_type(8))) unsigned short ushort8;
typedef __attribute__((ext_vector_type(4))) float floatx4;

__device__ __forceinline__ void gload_lds16(const void* g, void* l) {
  __builtin_amdgcn_global_load_lds(
      (const __attribute__((address_space(1))) unsigned int*)g,
      (__attribute__((address_space(3))) unsigned int*)l, 16, 0, 0);
}

__device__ __forceinline__ ushort_t f2bf(float v) {
  __hip_bfloat16 h = __float2bfloat16(v);
  return __builtin_bit_cast(unsigned short, h);
}

// ---------------------------------------------------------------- gating ----
__global__ __launch_bounds__(256) void gate_cast_k(
    const float* __restrict__ x, const float* __restrict__ gamma,
    const float* __restrict__ beta, const float* __restrict__ Wg,
    ushort_t* __restrict__ xb, int2* __restrict__ gidx, float2* __restrict__ gw)
{
  const int row  = (blockIdx.x * blockDim.x + threadIdx.x) >> 6;
  const int lane = threadIdx.x & 63;
  const float* xr = x + (size_t)row * I_DIM + lane * 8;
  float4 a = *(const float4*)(xr);
  float4 b = *(const float4*)(xr + 4);
  float xs[8] = {a.x, a.y, a.z, a.w, b.x, b.y, b.z, b.w};

  float s = 0.f;
#pragma unroll
  for (int j = 0; j < 8; ++j) s += xs[j];
#pragma unroll
  for (int off = 32; off; off >>= 1) s += __shfl_xor(s, off);
  const float mu = s * (1.0f / I_DIM);

  float vs = 0.f;
#pragma unroll
  for (int j = 0; j < 8; ++j) { float d = xs[j] - mu; vs += d * d; }
#pragma unroll
  for (int off = 32; off; off >>= 1) vs += __shfl_xor(vs, off);
  const float rstd = rsqrtf(vs * (1.0f / I_DIM) + 1e-5f);

  float lg[8] = {0.f, 0.f, 0.f, 0.f, 0.f, 0.f, 0.f, 0.f};
  const float* gmr = gamma + lane * 8;
  const float* btr = beta + lane * 8;
#pragma unroll
  for (int j = 0; j < 8; ++j) {
    const float y = (xs[j] - mu) * rstd * gmr[j] + btr[j];
    const float* wr = Wg + (size_t)(lane * 8 + j) * E_NUM;
#pragma unroll
    for (int e = 0; e < 8; ++e) lg[e] += y * wr[e];
  }
#pragma unroll
  for (int e = 0; e < 8; ++e)
#pragma unroll
    for (int off = 32; off; off >>= 1) lg[e] += __shfl_xor(lg[e], off);

  ushort8 o;
#pragma unroll
  for (int j = 0; j < 8; ++j) o[j] = f2bf(xs[j]);
  *(ushort8*)(xb + (size_t)row * I_DIM + lane * 8) = o;

  if (lane == 0) {
    int i0 = 0; float b0 = lg[0];
#pragma unroll
    for (int e = 1; e < 8; ++e) if (lg[e] > b0) { b0 = lg[e]; i0 = e; }
    int i1 = -1; float b1 = -3.4e38f;
#pragma unroll
    for (int e = 0; e < 8; ++e) if (e != i0 && lg[e] > b1) { b1 = lg[e]; i1 = e; }
    const float w0 = 1.0f / (1.0f + __expf(b1 - b0));
    gidx[row] = make_int2(i0, i1);
    gw[row] = make_float2(w0, 1.0f - w0);
  }
}

// ------------------------------------------------------------ assignment ----
__global__ __launch_bounds__(256) void assign_k(
    const int2* __restrict__ gidx, const float2* __restrict__ gw,
    int* __restrict__ rowmap, float* __restrict__ wmap,
    int* __restrict__ cursor)
{
  __shared__ int lcnt[E_NUM];
  __shared__ int lbase[E_NUM];
  const int tid = threadIdx.x;
  const int row = blockIdx.x * 256 + tid;
  if (tid < E_NUM) lcnt[tid] = 0;
  __syncthreads();
  const int2 g = gidx[row];
  const float2 w = gw[row];
  const int r0 = atomicAdd(&lcnt[g.x], 1);
  const int r1 = atomicAdd(&lcnt[g.y], 1);
  __syncthreads();
  if (tid < E_NUM) lbase[tid] = atomicAdd(&cursor[tid], lcnt[tid]);
  __syncthreads();
  const int p0 = g.x * CAP + lbase[g.x] + r0;
  rowmap[p0] = row; wmap[p0] = w.x;
  const int p1 = g.y * CAP + lbase[g.y] + r1;
  rowmap[p1] = row; wmap[p1] = w.y;
}

// ------------------------------------------------- weight transpose+cast ----
__global__ __launch_bounds__(256) void transpose_cast_k(
    const float* __restrict__ src, ushort_t* __restrict__ dst,
    int R, int C, size_t srcBStr, size_t dstBStr)
{
  __shared__ float tile[32][33];
  src += (size_t)blockIdx.z * srcBStr;
  dst += (size_t)blockIdx.z * dstBStr;
  const int c0 = blockIdx.x * 32, r0 = blockIdx.y * 32;
  const int tx = threadIdx.x, ty = threadIdx.y;
#pragma unroll
  for (int i = 0; i < 4; ++i)
    tile[ty + i * 8][tx] = src[(size_t)(r0 + ty + i * 8) * C + c0 + tx];
  __syncthreads();
#pragma unroll
  for (int i = 0; i < 4; ++i) {
    const int c = c0 + ty + i * 8;
    if (c < C) dst[(size_t)c * R + r0 + tx] = f2bf(tile[tx][ty + i * 8]);
  }
}

// ------------------------------------------------------- fused chain GEMM ---
// z LDS layout: byte(m, kb) = m*1024 + (kb ^ ((m&7)<<4))   (XOR involution,
// applied identically at init-staging, frag reads, and writeback).

// One hidden layer: z = act(z @ W^T), W given as [N][K] bf16.
// Swapped-operand MFMA: acc[nf][mf] holds D[n][m], n = n0+nf*16+q*4+r,
// m = mf*16+fr.  Reads z (all waves), then barrier, overwrite z, barrier.
template <int NF, bool RELU>
__device__ __forceinline__ void layer_z(
    const ushort_t* __restrict__ Wt, char* __restrict__ z,
    int n0, int fr, int q)
{
  const ushort_t* wb[NF];
#pragma unroll
  for (int nf = 0; nf < NF; ++nf)
    wb[nf] = Wt + (size_t)(n0 + nf * 16 + fr) * 512 + q * 8;

  bf16x8 Wr[2][NF];
#pragma unroll
  for (int nf = 0; nf < NF; ++nf) Wr[0][nf] = *(const bf16x8*)(wb[nf]);

  floatx4 acc[NF][4] = {};
#pragma unroll
  for (int s = 0; s < 16; ++s) {
    if (s < 15) {
#pragma unroll
      for (int nf = 0; nf < NF; ++nf)
        Wr[(s + 1) & 1][nf] = *(const bf16x8*)(wb[nf] + (s + 1) * 32);
    }
#pragma unroll
    for (int mf = 0; mf < 4; ++mf) {
      const int m = mf * 16 + fr;
      const bf16x8 zf = *(const bf16x8*)(
          z + m * 1024 + ((s * 64 + q * 16) ^ ((m & 7) << 4)));
#pragma unroll
      for (int nf = 0; nf < NF; ++nf)
        acc[nf][mf] = __builtin_amdgcn_mfma_f32_16x16x32_bf16(
            Wr[s & 1][nf], zf, acc[nf][mf], 0, 0, 0);
    }
  }

  // pack to regs (lane: 4 consecutive n per (nf,mf) at fixed m)
  ushort4 st[NF][4];
#pragma unroll
  for (int nf = 0; nf < NF; ++nf)
#pragma unroll
    for (int mf = 0; mf < 4; ++mf) {
      float v0 = acc[nf][mf][0], v1 = acc[nf][mf][1];
      float v2 = acc[nf][mf][2], v3 = acc[nf][mf][3];
      if (RELU) {
        v0 = fmaxf(v0, 0.f); v1 = fmaxf(v1, 0.f);
        v2 = fmaxf(v2, 0.f); v3 = fmaxf(v3, 0.f);
      }
      st[nf][mf] = make_ushort4(f2bf(v0), f2bf(v1), f2bf(v2), f2bf(v3));
    }

  __syncthreads();   // all waves finished READING z
#pragma unroll
  for (int nf = 0; nf < NF; ++nf) {
    const int nbyte = (n0 + nf * 16 + q * 4) * 2;
#pragma unroll
    for (int mf = 0; mf < 4; ++mf) {
      const int m = mf * 16 + fr;
      *(ushort4*)(z + m * 1024 + (nbyte ^ ((m & 7) << 4))) = st[nf][mf];
    }
  }
  __syncthreads();   // writes visible to all waves
}

// Final layer: theta = z @ Wout^T, combine with gate weight, scatter+split.
template <int NF>
__device__ __forceinline__ void layer_final(
    const ushort_t* __restrict__ Wt, const char* __restrict__ z,
    int n0, int zr0, const int* __restrict__ rowmap,
    const float* __restrict__ wmap, float* __restrict__ out,
    int fr, int q)
{
  const ushort_t* wb[NF];
#pragma unroll
  for (int nf = 0; nf < NF; ++nf)
    wb[nf] = Wt + (size_t)(n0 + nf * 16 + fr) * 512 + q * 8;

  bf16x8 Wr[2][NF];
#pragma unroll
  for (int nf = 0; nf < NF; ++nf) Wr[0][nf] = *(const bf16x8*)(wb[nf]);

  floatx4 acc[NF][4] = {};
#pragma unroll
  for (int s = 0; s < 16; ++s) {
    if (s < 15) {
#pragma unroll
      for (int nf = 0; nf < NF; ++nf)
        Wr[(s + 1) & 1][nf] = *(const bf16x8*)(wb[nf] + (s + 1) * 32);
    }
#pragma unroll
    for (int mf = 0; mf < 4; ++mf) {
      const int m = mf * 16 + fr;
      const bf16x8 zf = *(const bf16x8*)(
          z + m * 1024 + ((s * 64 + q * 16) ^ ((m & 7) << 4)));
#pragma unroll
      for (int nf = 0; nf < NF; ++nf)
        acc[nf][mf] = __builtin_amdgcn_mfma_f32_16x16x32_bf16(
            Wr[s & 1][nf], zf, acc[nf][mf], 0, 0, 0);
    }
  }

#pragma unroll
  for (int mf = 0; mf < 4; ++mf) {
    const int m = mf * 16 + fr;
    const float wgt = wmap[zr0 + m];
    if (wgt != 0.0f) {
      const size_t orig = rowmap[zr0 + m];
#pragma unroll
      for (int nf = 0; nf < NF; ++nf)
#pragma unroll
        for (int r = 0; r < 4; ++r) {
          const int col = n0 + nf * 16 + q * 4 + r;
          if (col < T_DIM) {
            const float v = acc[nf][mf][r] * wgt;
            float* dst = (col < I_DIM)
                ? out + orig * I_DIM + col
                : out + (size_t)B_ROWS * I_DIM + orig * (T_DIM - I_DIM) +
                      (col - I_DIM);
            atomicAdd(dst, v);
          }
        }
    }
  }
}

__global__ __launch_bounds__(256, 2) void moe_chain_k(
    const ushort_t* __restrict__ xb, const ushort_t* __restrict__ W0t,
    const ushort_t* __restrict__ Wmidt, const ushort_t* __restrict__ Woutt,
    const int* __restrict__ rowmap, const float* __restrict__ wmap,
    const int* __restrict__ cursor, float* __restrict__ out)
{
  __shared__ char zb[64 * 1024];   // 64 rows x 512 bf16, swizzled

  const int b = blockIdx.x;
  const int e = b & 7;             // XCD-affine expert mapping
  const int lt = b >> 3;           // 0..35
  if (lt * 64 >= cursor[e]) return;  // dead (all-pad) tile
  const int zr0 = e * CAP + lt * 64;

  const int tid = threadIdx.x, wid = tid >> 6, lane = tid & 63;
  const int fr = lane & 15, q = lane >> 4;

  // init: stage 64 gathered x rows into z (swizzle via source permutation:
  // lds dest is linear, global slot = lds_slot ^ (row&7) — same involution
  // as the read-side XOR).
#pragma unroll
  for (int i = 0; i < 16; ++i) {
    const int r = wid * 16 + i;
    const ushort_t* src = xb + (size_t)rowmap[zr0 + r] * 512 +
                          ((lane ^ (r & 7)) * 8);
    gload_lds16(src, zb + r * 1024);
  }
  __syncthreads();

  const size_t SQ = (size_t)512 * 512;
  const int n0 = wid * 128;
  layer_z<8, false>(W0t + (size_t)e * SQ, zb, n0, fr, q);
  layer_z<8, true>(Wmidt + (size_t)(0 * E_NUM + e) * SQ, zb, n0, fr, q);
  layer_z<8, true>(Wmidt + (size_t)(1 * E_NUM + e) * SQ, zb, n0, fr, q);
  layer_z<8, true>(Wmidt + (size_t)(2 * E_NUM + e) * SQ, zb, n0, fr, q);

  const ushort_t* We = Woutt + (size_t)e * T_PAD * 512;
  layer_final<5>(We, zb, wid * 160,      zr0, rowmap, wmap, out, fr, q);
  layer_final<5>(We, zb, wid * 160 + 80, zr0, rowmap, wmap, out, fr, q);
}

// ---------------------------------------------------------------- launch ----
extern "C" void kernel_launch(void* const* d_in, const int* in_sizes, int n_in,
                              void* d_out, int out_size, void* d_ws,
                              size_t ws_size, hipStream_t stream) {
  const float* x     = (const float*)d_in[0];
  const float* gamma = (const float*)d_in[1];
  const float* beta  = (const float*)d_in[2];
  const float* Wg    = (const float*)d_in[3];
  const float* W0    = (const float*)d_in[4];
  const float* Wmid  = (const float*)d_in[5];
  const float* Wout  = (const float*)d_in[6];
  float* out = (float*)d_out;

  char* ws = (char*)d_ws;
  size_t off = 0;
  auto alloc = [&](size_t bytes) -> char* {
    char* p = ws + off;
    off += (bytes + 255) & ~(size_t)255;
    return p;
  };

  const size_t SQ = (size_t)H_DIM * H_DIM;
  ushort_t* xb    = (ushort_t*)alloc((size_t)B_ROWS * I_DIM * 2);
  ushort_t* W0t   = (ushort_t*)alloc((size_t)E_NUM * SQ * 2);
  ushort_t* Wmidt = (ushort_t*)alloc((size_t)3 * E_NUM * SQ * 2);
  ushort_t* Woutt = (ushort_t*)alloc((size_t)E_NUM * T_PAD * H_DIM * 2);
  int2*   gidx  = (int2*)alloc((size_t)B_ROWS * sizeof(int2));
  float2* gwv   = (float2*)alloc((size_t)B_ROWS * sizeof(float2));
  int*   rmap   = (int*)alloc(NPAD * sizeof(int));
  float* wmap   = (float*)alloc(NPAD * sizeof(float));
  int*   cursor = (int*)alloc(E_NUM * sizeof(int));

  hipMemsetAsync(d_out, 0, (size_t)out_size * sizeof(float), stream);
  hipMemsetAsync(rmap, 0, NPAD * sizeof(int), stream);
  hipMemsetAsync(wmap, 0, NPAD * sizeof(float), stream);
  hipMemsetAsync(cursor, 0, E_NUM * sizeof(int), stream);

  gate_cast_k<<<dim3(B_ROWS / 4), 256, 0, stream>>>(x, gamma, beta, Wg, xb,
                                                    gidx, gwv);
  transpose_cast_k<<<dim3(16, 16, 8), dim3(32, 8), 0, stream>>>(
      W0, W0t, 512, 512, SQ, SQ);
  transpose_cast_k<<<dim3(16, 16, 24), dim3(32, 8), 0, stream>>>(
      Wmid, Wmidt, 512, 512, SQ, SQ);
  transpose_cast_k<<<dim3(19, 16, 8), dim3(32, 8), 0, stream>>>(
      Wout, Woutt, 512, 608, (size_t)512 * 608, (size_t)T_PAD * 512);
  assign_k<<<dim3(B_ROWS / 256), 256, 0, stream>>>(gidx, gwv, rmap, wmap,
                                                   cursor);

  moe_chain_k<<<dim3(NB), 256, 0, stream>>>(xb, W0t, Wmidt, Woutt, rmap, wmap,
                                            cursor, out);
}

// Round 3
// 260.034 us; speedup vs baseline: 1.5974x; 1.5974x over previous
//
#include <hip/hip_runtime.h>
#include <hip/hip_bf16.h>
#include <stdint.h>

// NBEATS MoE block — round 7: back to 5-dispatch grouped GEMM, tiles resized
// for TLP. Round-6 post-mortem: fusion gave 1 wave/SIMD (zero latency
// hiding), uncoalesced atomic scatter (WRITE 5x), bank conflicts — 288us.
// Round-4's limiter was occupancy (576 blocks = 2.25/CU) + per-step drain.
// This round:
//   - 64x128 tiles -> 1152/1440 blocks (4.5/CU grid), LDS 48KB -> 3
//     blocks/CU co-resident, __launch_bounds__(256,3).
//   - 2-phase double-buffer (verified round 5): stage t+1 before compute t,
//     one vmcnt(0)+s_barrier per K-step.
//   - BK=64 + verified XOR-swizzle pair (0 conflicts in round 5).
//   - round-4 epilogues (coalesced z write; coalesced atomic scatter).
// Expert map e = t&7 keeps each expert's weight panel XCD-local.

#define B_ROWS 8192
#define I_DIM  512
#define H_DIM  512
#define E_NUM  8
#define T_DIM  608
#define T_PAD  640
#define CAP    2304   // rows per expert segment (capacity)
#define TPW    36     // 64-row tiles per expert = CAP/64
#define MT     288    // M-tiles total = E_NUM*TPW
#define NPAD   18432  // CAP*E_NUM

typedef unsigned short ushort_t;
typedef __attribute__((ext_vector_type(8))) __bf16 bf16x8;
typedef __attribute__((ext_vector_type(8))) unsigned short ushort8;
typedef __attribute__((ext_vector_type(4))) float floatx4;

__device__ __forceinline__ void gload_lds16(const void* g, void* l) {
  __builtin_amdgcn_global_load_lds(
      (const __attribute__((address_space(1))) unsigned int*)g,
      (__attribute__((address_space(3))) unsigned int*)l, 16, 0, 0);
}

__device__ __forceinline__ ushort_t f2bf(float v) {
  __hip_bfloat16 h = __float2bfloat16(v);
  return __builtin_bit_cast(unsigned short, h);
}

// ---------------------------------------------------------------- gating ----
__global__ __launch_bounds__(256) void gate_cast_k(
    const float* __restrict__ x, const float* __restrict__ gamma,
    const float* __restrict__ beta, const float* __restrict__ Wg,
    ushort_t* __restrict__ xb, int2* __restrict__ gidx, float2* __restrict__ gw)
{
  const int row  = (blockIdx.x * blockDim.x + threadIdx.x) >> 6;
  const int lane = threadIdx.x & 63;
  const float* xr = x + (size_t)row * I_DIM + lane * 8;
  float4 a = *(const float4*)(xr);
  float4 b = *(const float4*)(xr + 4);
  float xs[8] = {a.x, a.y, a.z, a.w, b.x, b.y, b.z, b.w};

  float s = 0.f;
#pragma unroll
  for (int j = 0; j < 8; ++j) s += xs[j];
#pragma unroll
  for (int off = 32; off; off >>= 1) s += __shfl_xor(s, off);
  const float mu = s * (1.0f / I_DIM);

  float vs = 0.f;
#pragma unroll
  for (int j = 0; j < 8; ++j) { float d = xs[j] - mu; vs += d * d; }
#pragma unroll
  for (int off = 32; off; off >>= 1) vs += __shfl_xor(vs, off);
  const float rstd = rsqrtf(vs * (1.0f / I_DIM) + 1e-5f);

  float lg[8] = {0.f, 0.f, 0.f, 0.f, 0.f, 0.f, 0.f, 0.f};
  const float* gmr = gamma + lane * 8;
  const float* btr = beta + lane * 8;
#pragma unroll
  for (int j = 0; j < 8; ++j) {
    const float y = (xs[j] - mu) * rstd * gmr[j] + btr[j];
    const float* wr = Wg + (size_t)(lane * 8 + j) * E_NUM;
#pragma unroll
    for (int e = 0; e < 8; ++e) lg[e] += y * wr[e];
  }
#pragma unroll
  for (int e = 0; e < 8; ++e)
#pragma unroll
    for (int off = 32; off; off >>= 1) lg[e] += __shfl_xor(lg[e], off);

  ushort8 o;
#pragma unroll
  for (int j = 0; j < 8; ++j) o[j] = f2bf(xs[j]);
  *(ushort8*)(xb + (size_t)row * I_DIM + lane * 8) = o;

  if (lane == 0) {
    int i0 = 0; float b0 = lg[0];
#pragma unroll
    for (int e = 1; e < 8; ++e) if (lg[e] > b0) { b0 = lg[e]; i0 = e; }
    int i1 = -1; float b1 = -3.4e38f;
#pragma unroll
    for (int e = 0; e < 8; ++e) if (e != i0 && lg[e] > b1) { b1 = lg[e]; i1 = e; }
    const float w0 = 1.0f / (1.0f + __expf(b1 - b0));
    gidx[row] = make_int2(i0, i1);
    gw[row] = make_float2(w0, 1.0f - w0);
  }
}

// ------------------------------------------------------------ assignment ----
__global__ __launch_bounds__(256) void assign_k(
    const int2* __restrict__ gidx, const float2* __restrict__ gw,
    int* __restrict__ rowmap, float* __restrict__ wmap,
    int* __restrict__ cursor)
{
  __shared__ int lcnt[E_NUM];
  __shared__ int lbase[E_NUM];
  const int tid = threadIdx.x;
  const int row = blockIdx.x * 256 + tid;
  if (tid < E_NUM) lcnt[tid] = 0;
  __syncthreads();
  const int2 g = gidx[row];
  const float2 w = gw[row];
  const int r0 = atomicAdd(&lcnt[g.x], 1);
  const int r1 = atomicAdd(&lcnt[g.y], 1);
  __syncthreads();
  if (tid < E_NUM) lbase[tid] = atomicAdd(&cursor[tid], lcnt[tid]);
  __syncthreads();
  const int p0 = g.x * CAP + lbase[g.x] + r0;
  rowmap[p0] = row; wmap[p0] = w.x;
  const int p1 = g.y * CAP + lbase[g.y] + r1;
  rowmap[p1] = row; wmap[p1] = w.y;
}

// ------------------------------------------------- weight transpose+cast ----
__global__ __launch_bounds__(256) void transpose_cast_k(
    const float* __restrict__ src, ushort_t* __restrict__ dst,
    int R, int C, size_t srcBStr, size_t dstBStr)
{
  __shared__ float tile[32][33];
  src += (size_t)blockIdx.z * srcBStr;
  dst += (size_t)blockIdx.z * dstBStr;
  const int c0 = blockIdx.x * 32, r0 = blockIdx.y * 32;
  const int tx = threadIdx.x, ty = threadIdx.y;
#pragma unroll
  for (int i = 0; i < 4; ++i)
    tile[ty + i * 8][tx] = src[(size_t)(r0 + ty + i * 8) * C + c0 + tx];
  __syncthreads();
#pragma unroll
  for (int i = 0; i < 4; ++i) {
    const int c = c0 + ty + i * 8;
    if (c < C) dst[(size_t)c * R + r0 + tx] = f2bf(tile[tx][ty + i * 8]);
  }
}

// ------------------------------------------------------------------ GEMM ----
// 64x128 tile, 4 waves (2M x 2N), BK=64, 2-phase double-buffer, swizzled.
// blockIdx.x = M-tile t: expert e = t&7 (XCD-affine), lt = t>>3,
// slot rows zr0 = e*CAP + lt*64.  blockIdx.y = 128-col N panel.
template <bool GATHER, bool RELU, bool FINAL>
__global__ __launch_bounds__(256, 3) void gemm_k(
    const ushort_t* __restrict__ A,      // GATHER: xb [8192][K]; else z [NPAD][K]
    const ushort_t* __restrict__ B,      // bf16 [E][N][K]
    size_t bEStr,
    const int* __restrict__ rowmap, const float* __restrict__ wmap,
    const int* __restrict__ cursor,      // live counts per expert
    ushort_t* __restrict__ Z,            // mid out [NPAD][H_DIM]
    float* __restrict__ out)             // final out (split)
{
  constexpr int K = 512;
  constexpr int BK = 64;                 // elems per K-step (128B rows)
  constexpr int NSTEP = K / BK;          // 8
  __shared__ char lA[2][64 * 128];       // 2 x 8KB
  __shared__ char lB[2][128 * 128];      // 2 x 16KB
  __shared__ float wrow[64];
  __shared__ int rrow[64];

  const int t = blockIdx.x;
  const int e = t & 7;                   // XCD-affine expert mapping
  const int lt = t >> 3;
  if (lt * 64 >= cursor[e]) return;      // dead (all-pad) tile
  const int zr0 = e * CAP + lt * 64;
  const int bn0 = blockIdx.y * 128;

  const int tid = threadIdx.x, wid = tid >> 6, lane = tid & 63;
  // staging decomposition: thread -> (row-in-32-group, 16B k-slot)
  const int sr = tid >> 3;               // 0..31
  const int sk = tid & 7;                // 0..7

  const ushort_t* Bb = B + (size_t)e * bEStr + (size_t)bn0 * K;
  const ushort_t* gA[2];
  const ushort_t* gB[4];
#pragma unroll
  for (int p = 0; p < 2; ++p) {
    const int r = p * 32 + sr;
    int grow;
    if (GATHER) grow = rowmap[zr0 + r];
    else        grow = zr0 + r;
    gA[p] = A + (size_t)grow * K + ((sk ^ (r & 7)) * 8);   // pre-swizzled src
  }
#pragma unroll
  for (int p = 0; p < 4; ++p) {
    const int r = p * 32 + sr;
    gB[p] = Bb + (size_t)r * K + ((sk ^ (r & 7)) * 8);
  }

  auto stage = [&](int tt) {
    char* da = lA[tt & 1];
    char* db = lB[tt & 1];
    const int k0 = tt * BK;
#pragma unroll
    for (int p = 0; p < 2; ++p)
      gload_lds16(gA[p] + k0, da + (p * 32 + sr) * 128 + sk * 16);
#pragma unroll
    for (int p = 0; p < 4; ++p)
      gload_lds16(gB[p] + k0, db + (p * 32 + sr) * 128 + sk * 16);
  };

  floatx4 acc[2][4] = {};
  const int wm = (wid >> 1) * 32, wn = (wid & 1) * 64;
  const int fr = lane & 15, q = lane >> 4;

  stage(0);
  asm volatile("s_waitcnt vmcnt(0)" ::: "memory");
  __builtin_amdgcn_s_barrier();

#pragma unroll
  for (int step = 0; step < NSTEP; ++step) {
    const int cur = step & 1;
    if (step < NSTEP - 1) stage(step + 1);   // next tile in flight under MFMA

    bf16x8 af[2][2], bfr[4][2];
    const char* bA = lA[cur];
    const char* bB = lB[cur];
#pragma unroll
    for (int mi = 0; mi < 2; ++mi) {
      const int row = wm + mi * 16 + fr;
      const int rb = row * 128, rx = (row & 7) << 4;
#pragma unroll
      for (int kk = 0; kk < 2; ++kk)
        af[mi][kk] = *(const bf16x8*)(bA + ((rb + kk * 64 + q * 16) ^ rx));
    }
#pragma unroll
    for (int ni = 0; ni < 4; ++ni) {
      const int row = wn + ni * 16 + fr;
      const int rb = row * 128, rx = (row & 7) << 4;
#pragma unroll
      for (int kk = 0; kk < 2; ++kk)
        bfr[ni][kk] = *(const bf16x8*)(bB + ((rb + kk * 64 + q * 16) ^ rx));
    }
#pragma unroll
    for (int kk = 0; kk < 2; ++kk)
#pragma unroll
      for (int mi = 0; mi < 2; ++mi)
#pragma unroll
        for (int ni = 0; ni < 4; ++ni)
          acc[mi][ni] = __builtin_amdgcn_mfma_f32_16x16x32_bf16(
              af[mi][kk], bfr[ni][kk], acc[mi][ni], 0, 0, 0);

    if (step < NSTEP - 1) {
      asm volatile("s_waitcnt vmcnt(0)" ::: "memory");
      __builtin_amdgcn_s_barrier();
    }
  }

  if (!FINAL) {
    // C/D layout: col = lane&15, row = (lane>>4)*4 + reg (m89-verified)
    ushort_t* Zb = Z + (size_t)zr0 * H_DIM + bn0;
#pragma unroll
    for (int mi = 0; mi < 2; ++mi)
#pragma unroll
      for (int r = 0; r < 4; ++r) {
        const int row = wm + mi * 16 + q * 4 + r;
        ushort_t* zr = Zb + (size_t)row * H_DIM + wn + fr;
#pragma unroll
        for (int ni = 0; ni < 4; ++ni) {
          float v = acc[mi][ni][r];
          if (RELU) v = fmaxf(v, 0.0f);
          zr[ni * 16] = f2bf(v);
        }
      }
  } else {
    if (tid < 64) {
      wrow[tid] = wmap[zr0 + tid];
      rrow[tid] = rowmap[zr0 + tid];
    }
    __syncthreads();
#pragma unroll
    for (int mi = 0; mi < 2; ++mi)
#pragma unroll
      for (int r = 0; r < 4; ++r) {
        const int row = wm + mi * 16 + q * 4 + r;
        const float w = wrow[row];
        if (w != 0.0f) {
          const size_t orig = rrow[row];
#pragma unroll
          for (int ni = 0; ni < 4; ++ni) {
            const int col = bn0 + wn + ni * 16 + fr;
            if (col < T_DIM) {
              const float v = acc[mi][ni][r] * w;
              float* dst = (col < I_DIM)
                  ? out + orig * I_DIM + col
                  : out + (size_t)B_ROWS * I_DIM + orig * (T_DIM - I_DIM) +
                        (col - I_DIM);
              atomicAdd(dst, v);
            }
          }
        }
      }
  }
}

// ---------------------------------------------------------------- launch ----
extern "C" void kernel_launch(void* const* d_in, const int* in_sizes, int n_in,
                              void* d_out, int out_size, void* d_ws,
                              size_t ws_size, hipStream_t stream) {
  const float* x     = (const float*)d_in[0];
  const float* gamma = (const float*)d_in[1];
  const float* beta  = (const float*)d_in[2];
  const float* Wg    = (const float*)d_in[3];
  const float* W0    = (const float*)d_in[4];
  const float* Wmid  = (const float*)d_in[5];
  const float* Wout  = (const float*)d_in[6];
  float* out = (float*)d_out;

  char* ws = (char*)d_ws;
  size_t off = 0;
  auto alloc = [&](size_t bytes) -> char* {
    char* p = ws + off;
    off += (bytes + 255) & ~(size_t)255;
    return p;
  };

  const size_t SQ = (size_t)H_DIM * H_DIM;
  ushort_t* xb    = (ushort_t*)alloc((size_t)B_ROWS * I_DIM * 2);
  ushort_t* W0t   = (ushort_t*)alloc((size_t)E_NUM * SQ * 2);
  ushort_t* Wmidt = (ushort_t*)alloc((size_t)3 * E_NUM * SQ * 2);
  ushort_t* Woutt = (ushort_t*)alloc((size_t)E_NUM * T_PAD * H_DIM * 2);
  int2*   gidx  = (int2*)alloc((size_t)B_ROWS * sizeof(int2));
  float2* gwv   = (float2*)alloc((size_t)B_ROWS * sizeof(float2));
  int*   rmap   = (int*)alloc(NPAD * sizeof(int));
  float* wmap   = (float*)alloc(NPAD * sizeof(float));
  int*   cursor = (int*)alloc(E_NUM * sizeof(int));
  ushort_t* z0 = (ushort_t*)alloc((size_t)NPAD * H_DIM * 2);
  ushort_t* z1 = (ushort_t*)alloc((size_t)NPAD * H_DIM * 2);

  hipMemsetAsync(d_out, 0, (size_t)out_size * sizeof(float), stream);
  hipMemsetAsync(rmap, 0, NPAD * sizeof(int), stream);
  hipMemsetAsync(wmap, 0, NPAD * sizeof(float), stream);
  hipMemsetAsync(cursor, 0, E_NUM * sizeof(int), stream);

  gate_cast_k<<<dim3(B_ROWS / 4), 256, 0, stream>>>(x, gamma, beta, Wg, xb,
                                                    gidx, gwv);
  transpose_cast_k<<<dim3(16, 16, 8), dim3(32, 8), 0, stream>>>(
      W0, W0t, 512, 512, SQ, SQ);
  transpose_cast_k<<<dim3(16, 16, 24), dim3(32, 8), 0, stream>>>(
      Wmid, Wmidt, 512, 512, SQ, SQ);
  transpose_cast_k<<<dim3(19, 16, 8), dim3(32, 8), 0, stream>>>(
      Wout, Woutt, 512, 608, (size_t)512 * 608, (size_t)T_PAD * 512);
  assign_k<<<dim3(B_ROWS / 256), 256, 0, stream>>>(gidx, gwv, rmap, wmap,
                                                   cursor);

  const dim3 gmid(MT, H_DIM / 128);
  const dim3 gfin(MT, T_PAD / 128);
  // z0 = gather(x) @ W0   (no relu)
  gemm_k<true, false, false><<<gmid, 256, 0, stream>>>(
      xb, W0t, SQ, rmap, wmap, cursor, z0, nullptr);
  // z1 = relu(z0 @ Wmid[0])
  gemm_k<false, true, false><<<gmid, 256, 0, stream>>>(
      z0, Wmidt + 0 * E_NUM * SQ, SQ, rmap, wmap, cursor, z1, nullptr);
  // z0 = relu(z1 @ Wmid[1])
  gemm_k<false, true, false><<<gmid, 256, 0, stream>>>(
      z1, Wmidt + 1 * E_NUM * SQ, SQ, rmap, wmap, cursor, z0, nullptr);
  // z1 = relu(z0 @ Wmid[2])
  gemm_k<false, true, false><<<gmid, 256, 0, stream>>>(
      z0, Wmidt + 2 * E_NUM * SQ, SQ, rmap, wmap, cursor, z1, nullptr);
  // out += gate_w * (z1 @ Wout), scattered + split backcast/forecast
  gemm_k<false, false, true><<<gfin, 256, 0, stream>>>(
      z1, Woutt, (size_t)T_PAD * H_DIM, rmap, wmap, cursor, nullptr, out);
}